// Round 3
// baseline (52.902 us; speedup 1.0000x reference)
//
#include <hip/hip_runtime.h>
#include <stdint.h>

#define B_  8
#define C_  128
#define N_  8192
#define K_  16
#define O_  128

typedef __attribute__((ext_vector_type(8))) short short8;
typedef __attribute__((ext_vector_type(4))) float f32x4;

__device__ __forceinline__ unsigned short f2bf(float f) {
    union { float f; uint32_t u; } v; v.f = f;
    uint32_t u = v.u;
    return (unsigned short)((u + 0x7FFFu + ((u >> 16) & 1u)) >> 16);  // RNE
}

// Orderable-u16 map for bf16: neg -> ~u, pos -> u | 0x8000.
// Monotone bijection: unsigned compare == float compare. Applied pairwise on u32.
__device__ __forceinline__ uint32_t fwdmap(uint32_t u) {
    uint32_t s  = u & 0x80008000u;
    uint32_t xm = s - (s >> 15) + 0x80008000u;   // per-half: neg->0xFFFF, pos->0x8000
    return u ^ xm;
}
__device__ __forceinline__ uint32_t invmap(uint32_t v) {
    uint32_t s  = (~v) & 0x80008000u;            // transformed-neg has msb==0
    uint32_t xm = s - (s >> 15) + 0x80008000u;
    return v ^ xm;
}
__device__ __forceinline__ uint32_t pkmax(uint32_t a, uint32_t b) {
    uint32_t d;
    asm("v_pk_max_u16 %0, %1, %2" : "=v"(d) : "v"(a), "v"(b));
    return d;
}
__device__ __forceinline__ uint4 pkmax4(uint4 a, uint4 b) {
    return make_uint4(pkmax(a.x, b.x), pkmax(a.y, b.y),
                      pkmax(a.z, b.z), pkmax(a.w, b.w));
}

// Kernel 1: x (B, C, N) f32 -> xt (B*N, C) orderable-u16(bf16) row-major.
// LDS-staged transpose: coalesced reads along N, conflict-free LDS (pad 65),
// dense full-row 16B/lane writes.
__global__ __launch_bounds__(256) void k_transpose(const float* __restrict__ x,
                                                   unsigned short* __restrict__ xt) {
    __shared__ uint32_t lds[64 * 65];   // [c2][n_local]
    int t    = threadIdx.x;
    int lane = t & 63;
    int wv   = t >> 6;
    int blk  = blockIdx.x;            // 8 b * 128 ntiles
    int b    = blk >> 7;
    int n0   = (blk & 127) * 64;

    const float* xb = x + (size_t)b * C_ * N_ + n0 + lane;
    #pragma unroll
    for (int j = 0; j < 16; ++j) {
        int c2 = wv * 16 + j;
        float f0 = xb[(size_t)(2 * c2) * N_];
        float f1 = xb[(size_t)(2 * c2 + 1) * N_];
        uint32_t pk = (uint32_t)f2bf(f0) | ((uint32_t)f2bf(f1) << 16);
        lds[c2 * 65 + lane] = fwdmap(pk);
    }
    __syncthreads();

    int rl = lane >> 4;    // row-in-group 0..3
    int ch = lane & 15;    // 16B chunk of the 256B row
    #pragma unroll
    for (int it = 0; it < 4; ++it) {
        int r = it * 16 + wv * 4 + rl;
        uint32_t u0 = lds[(ch * 4 + 0) * 65 + r];
        uint32_t u1 = lds[(ch * 4 + 1) * 65 + r];
        uint32_t u2 = lds[(ch * 4 + 2) * 65 + r];
        uint32_t u3 = lds[(ch * 4 + 3) * 65 + r];
        *(uint4*)(xt + ((size_t)(b * N_ + n0 + r)) * C_ + ch * 8) =
            make_uint4(u0, u1, u2, u3);
    }
}

// Kernel 2: 64 points/block, grid 1024 (4 blocks/CU).
// Gather: lane = (point-in-group-of-4, 16B chunk); 16 independent uint4 loads
// then a depth-4 v_pk_max_u16 tree (4 ops/neighbor vs 24 with float unpack).
// Inverse map once per point -> bf16 bits straight into agg LDS.
// GEMM: wave owns 32 output rows x 64 points, W f32->bf16 into registers.
__global__ __launch_bounds__(256, 4) void k_main(const unsigned short* __restrict__ xt,
                                                 const int* __restrict__ idx,
                                                 const float* __restrict__ Wp,
                                                 const float* __restrict__ bp,
                                                 float* __restrict__ out) {
    __shared__ __align__(16) unsigned short agg[64 * 136];  // 17408 B
    __shared__ int idxs[64 * K_];                            // 4096 B

    int t    = threadIdx.x;
    int lane = t & 63;
    int wv   = t >> 6;
    int blk  = blockIdx.x;          // 8 b * 128 ntiles
    int b    = blk >> 7;
    int n0   = (blk & 127) * 64;
    size_t pbase = (size_t)b * N_ + n0;

    // ---- stage idx ----
    const int* ip = idx + pbase * K_;
    #pragma unroll
    for (int i = 0; i < 4; ++i) idxs[t + i * 256] = ip[t + i * 256];
    __syncthreads();

    // ---- gather + max: 16 points per wave, 4 points per iteration ----
    int pt  = lane >> 4;   // point within group of 4
    int cch = lane & 15;   // 16B chunk of 256B row
    #pragma unroll
    for (int i = 0; i < 4; ++i) {
        int p = wv * 16 + i * 4 + pt;
        const int* qq = &idxs[p * K_];
        uint4 d[16];
        #pragma unroll
        for (int k = 0; k < 16; ++k)
            d[k] = *(const uint4*)(xt + (size_t)qq[k] * C_ + cch * 8);
        #pragma unroll
        for (int s = 8; s >= 1; s >>= 1)
            #pragma unroll
            for (int k = 0; k < s; ++k)
                d[k] = pkmax4(d[k], d[k + s]);
        uint4 v = make_uint4(invmap(d[0].x), invmap(d[0].y),
                             invmap(d[0].z), invmap(d[0].w));
        *(uint4*)&agg[p * 136 + cch * 8] = v;
    }
    __syncthreads();

    // ---- MFMA GEMM: wave computes o in [wo, wo+32) x all 64 points ----
    int r16 = lane & 15;
    int h   = lane >> 4;
    int wo  = wv * 32;

    short8 af[2][4];
    #pragma unroll
    for (int ot2 = 0; ot2 < 2; ++ot2)
        #pragma unroll
        for (int kk = 0; kk < 4; ++kk) {
            const float* wr = Wp + (size_t)(wo + ot2 * 16 + r16) * C_ + kk * 32 + h * 8;
            float4 a0 = *(const float4*)wr;
            float4 a1 = *(const float4*)(wr + 4);
            short8 s;
            s[0] = (short)f2bf(a0.x); s[1] = (short)f2bf(a0.y);
            s[2] = (short)f2bf(a0.z); s[3] = (short)f2bf(a0.w);
            s[4] = (short)f2bf(a1.x); s[5] = (short)f2bf(a1.y);
            s[6] = (short)f2bf(a1.z); s[7] = (short)f2bf(a1.w);
            af[ot2][kk] = s;
        }
    float4 bb[2];
    bb[0] = *(const float4*)(bp + wo + h * 4);
    bb[1] = *(const float4*)(bp + wo + 16 + h * 4);

    const size_t ob = (size_t)b * O_ * N_ + n0;
    #pragma unroll
    for (int pt4 = 0; pt4 < 4; ++pt4) {
        short8 bfr[4];
        #pragma unroll
        for (int kk = 0; kk < 4; ++kk)
            bfr[kk] = *(const short8*)&agg[(pt4 * 16 + r16) * 136 + kk * 32 + h * 8];
        #pragma unroll
        for (int ot2 = 0; ot2 < 2; ++ot2) {
            f32x4 acc = {0.f, 0.f, 0.f, 0.f};
            #pragma unroll
            for (int kk = 0; kk < 4; ++kk)
                acc = __builtin_amdgcn_mfma_f32_16x16x32_bf16(af[ot2][kk], bfr[kk], acc, 0, 0, 0);
            // C/D layout: col = lane&15 (point), row = (lane>>4)*4 + reg
            int orow = wo + ot2 * 16 + h * 4;
            float* op = out + ob + (size_t)orow * N_ + pt4 * 16 + r16;
            float4 bv = bb[ot2];
            op[0]              = fmaxf(acc[0] + bv.x, 0.f);
            op[(size_t)N_]     = fmaxf(acc[1] + bv.y, 0.f);
            op[(size_t)2 * N_] = fmaxf(acc[2] + bv.z, 0.f);
            op[(size_t)3 * N_] = fmaxf(acc[3] + bv.w, 0.f);
        }
    }
}

extern "C" void kernel_launch(void* const* d_in, const int* in_sizes, int n_in,
                              void* d_out, int out_size, void* d_ws, size_t ws_size,
                              hipStream_t stream) {
    const float* x    = (const float*)d_in[0];
    const int*   idx  = (const int*)d_in[1];
    const float* W    = (const float*)d_in[2];
    const float* bias = (const float*)d_in[3];
    float* out = (float*)d_out;
    unsigned short* xt = (unsigned short*)d_ws;   // 65536 x 128 u16 = 16 MB

    hipLaunchKernelGGL(k_transpose, dim3(1024), dim3(256), 0, stream, x, xt);
    hipLaunchKernelGGL(k_main,      dim3(1024), dim3(256), 0, stream, xt, idx, W, bias, out);
}